// Round 7
// baseline (352.019 us; speedup 1.0000x reference)
//
#include <hip/hip_runtime.h>
#include <hip/hip_bf16.h>

#define B_   1024
#define N_   128
#define H_   128
#define FE_  8
#define G3_  384       // 3*H

typedef short s8v __attribute__((ext_vector_type(8)));   // 8 bf16 (4 VGPRs)
typedef float f4v __attribute__((ext_vector_type(4)));   // 4 fp32 accum

__device__ __forceinline__ unsigned short f2bf(float x) {  // RNE fp32->bf16
    unsigned int u = __float_as_uint(x);
    u += 0x7fffu + ((u >> 16) & 1u);
    return (unsigned short)(u >> 16);
}
__device__ __forceinline__ float bf2f(unsigned short s) {
    return __uint_as_float(((unsigned int)s) << 16);
}

// ---------------------------------------------------------------------------
// k0: split W_hh (384x128 f32) into hi/lo bf16 planes. hi+lo carries ~16
// mantissa bits; 3-product MFMA then gives fp32-class GEMM accuracy.
// ---------------------------------------------------------------------------
__global__ __launch_bounds__(256) void k0_split(
    const float* __restrict__ W, unsigned short* __restrict__ Whi,
    unsigned short* __restrict__ Wlo)
{
    const int i = blockIdx.x * 256 + threadIdx.x;   // grid covers exactly 49152
    const float x = W[i];
    const unsigned short hb = f2bf(x);
    Whi[i] = hb;
    Wlo[i] = f2bf(x - bf2f(hb));                    // x-hi exact (Sterbenz)
}

// ---------------------------------------------------------------------------
// k1: per-jet precompute (unchanged, fp32, audited).
//   hsum[b] = sum_n h[b,n,:]; message[b]=tanh(hsum.Wm^T + N*bm);
//   gi_base[b,g] = message[b].W_ih[g,0:128] + b_ih[g]
// ---------------------------------------------------------------------------
__global__ __launch_bounds__(256) void k1_prep(
    const float* __restrict__ h, const float* __restrict__ Wm,
    const float* __restrict__ bm, const float* __restrict__ W_ih,
    const float* __restrict__ b_ih, float* __restrict__ gi_base)
{
    const int b = blockIdx.x;
    const int t = threadIdx.x;

    __shared__ __align__(16) float4 part[256];
    __shared__ __align__(16) float  hsum[H_];
    __shared__ __align__(16) float  msg[H_];

    const float4* h4 = reinterpret_cast<const float4*>(h + (size_t)b * (N_ * H_));
    const int kc = t & 31;
    const int ng = t >> 5;
    float4 s = make_float4(0.f, 0.f, 0.f, 0.f);
    #pragma unroll
    for (int i = 0; i < 16; ++i) {
        float4 v = h4[(ng * 16 + i) * 32 + kc];
        s.x += v.x; s.y += v.y; s.z += v.z; s.w += v.w;
    }
    part[t] = s;
    __syncthreads();
    if (t < 32) {
        float4 a = part[t];
        #pragma unroll
        for (int g = 1; g < 8; ++g) {
            float4 v = part[g * 32 + t];
            a.x += v.x; a.y += v.y; a.z += v.z; a.w += v.w;
        }
        reinterpret_cast<float4*>(hsum)[t] = a;
    }
    __syncthreads();

    if (t < H_) {
        const float4* wr  = reinterpret_cast<const float4*>(Wm + t * H_);
        const float4* hs4 = reinterpret_cast<const float4*>(hsum);
        float d = 0.f;
        #pragma unroll
        for (int j = 0; j < 32; ++j) {
            float4 w = wr[j]; float4 x = hs4[j];
            d += w.x * x.x + w.y * x.y + w.z * x.z + w.w * x.w;
        }
        d += (float)N_ * bm[t];
        msg[t] = tanhf(d);
    }
    __syncthreads();

    for (int g = t; g < G3_; g += 256) {
        const float4* wr = reinterpret_cast<const float4*>(W_ih + g * (H_ + FE_));
        const float4* m4 = reinterpret_cast<const float4*>(msg);
        float d = 0.f;
        #pragma unroll
        for (int j = 0; j < 32; ++j) {
            float4 w = wr[j]; float4 x = m4[j];
            d += w.x * x.x + w.y * x.y + w.z * x.z + w.w * x.w;
        }
        gi_base[b * G3_ + g] = d + b_ih[g];
    }
}

// ---------------------------------------------------------------------------
// k2: gh = h @ W_hh^T via split-bf16 MFMA (16x16x32), fused GRU epilogue.
// Block: 64 rows x 384 cols, 4 waves. Wave wv owns H-col-tiles {wv*2, wv*2+1}
// and their matching gate triples (cols c, c+128, c+256) so gates stay local.
// Per wave: 2 row-pairs(rp) x 4 k-slices x 2 j x 3 gates x 2 rt x 3 MFMA = 288.
// A-tile fp32 in LDS, XOR-swizzled (row-stride 512B would 16-way conflict).
// MFMA layouts (m89-verified C/D + standard A/B):
//   A: lane provides row=(l&15), k=(l>>4)*8+e   (8 consecutive k)
//   B: lane provides col=(l&15), k=(l>>4)*8+e
//   D: lane reg r -> row=(l>>4)*4+r, col=(l&15)
// ---------------------------------------------------------------------------
__global__ __launch_bounds__(256) void k2_mfma(
    const float* __restrict__ h, const float* __restrict__ jets,
    const unsigned short* __restrict__ Whi, const unsigned short* __restrict__ Wlo,
    const float* __restrict__ b_hh, const float* __restrict__ W_ih,
    const float* __restrict__ gi_base, float* __restrict__ out)
{
    __shared__ __align__(16) float4 AsV[64 * 32];   // 32 KB fp32 A, swizzled
    const float* Asf = reinterpret_cast<const float*>(AsV);

    const int t    = threadIdx.x;
    const int row0 = blockIdx.x * 64;    // 64 rows, all within jet b
    const int b    = row0 >> 7;
    const int wv   = t >> 6;             // wave 0..3
    const int l    = t & 63;
    const int lr   = l & 15;             // A-row / B-col / D-col within tile
    const int lq   = l >> 4;             // k-chunk (inputs) / row-group (D)

    // stage A tile, swizzle float4-index: dst = f ^ (row&7)  (row = f>>5)
    {
        const float4* src = reinterpret_cast<const float4*>(h + (size_t)row0 * H_);
        #pragma unroll
        for (int i = 0; i < 8; ++i) {
            const int f = t + i * 256;
            AsV[f ^ ((f >> 5) & 7)] = src[f];
        }
    }
    __syncthreads();

    #pragma unroll
    for (int rp = 0; rp < 2; ++rp) {     // rows rp*32 .. rp*32+31
        f4v acc[2][2][3];                // [rt][j][gate], all-static indexing
        #pragma unroll
        for (int rt = 0; rt < 2; ++rt)
            #pragma unroll
            for (int j = 0; j < 2; ++j)
                #pragma unroll
                for (int g = 0; g < 3; ++g)
                    #pragma unroll
                    for (int e = 0; e < 4; ++e) acc[rt][j][g][e] = 0.f;

        #pragma unroll
        for (int ks = 0; ks < 4; ++ks) { // K-slices of 32
            // A-frags for both row-tiles: 2x ds_read_b128 (fp32) -> hi/lo cvt
            s8v aH[2], aL[2];
            #pragma unroll
            for (int rt = 0; rt < 2; ++rt) {
                const int r  = rp * 32 + rt * 16 + lr;
                const int f4 = r * 32 + ks * 8 + lq * 2;      // even
                const float4 x0 = AsV[f4 ^ (r & 7)];
                const float4 x1 = AsV[(f4 + 1) ^ (r & 7)];
                const float xs[8] = {x0.x, x0.y, x0.z, x0.w,
                                     x1.x, x1.y, x1.z, x1.w};
                #pragma unroll
                for (int e = 0; e < 8; ++e) {
                    const unsigned short hb = f2bf(xs[e]);
                    aH[rt][e] = (short)hb;
                    aL[rt][e] = (short)f2bf(xs[e] - bf2f(hb));
                }
            }
            #pragma unroll
            for (int j = 0; j < 2; ++j) {
                #pragma unroll
                for (int g = 0; g < 3; ++g) {
                    const int wrow = ((g << 7) + wv * 32 + j * 16 + lr) * H_
                                     + ks * 32 + lq * 8;       // 16B aligned
                    const s8v bH = *reinterpret_cast<const s8v*>(Whi + wrow);
                    const s8v bL = *reinterpret_cast<const s8v*>(Wlo + wrow);
                    #pragma unroll
                    for (int rt = 0; rt < 2; ++rt) {
                        acc[rt][j][g] = __builtin_amdgcn_mfma_f32_16x16x32_bf16(
                            aH[rt], bH, acc[rt][j][g], 0, 0, 0);
                        acc[rt][j][g] = __builtin_amdgcn_mfma_f32_16x16x32_bf16(
                            aH[rt], bL, acc[rt][j][g], 0, 0, 0);
                        acc[rt][j][g] = __builtin_amdgcn_mfma_f32_16x16x32_bf16(
                            aL[rt], bH, acc[rt][j][g], 0, 0, 0);
                    }
                }
            }
        }

        // ---- epilogue for rows rp*32..rp*32+31 ----
        #pragma unroll
        for (int rt = 0; rt < 2; ++rt) {
            float jf[4][8];              // jets for this thread's 4 rows
            #pragma unroll
            for (int ridx = 0; ridx < 4; ++ridx) {
                const int row = row0 + rp * 32 + rt * 16 + lq * 4 + ridx;
                const float4 j0 = *reinterpret_cast<const float4*>(jets + (size_t)row * FE_);
                const float4 j1 = *reinterpret_cast<const float4*>(jets + (size_t)row * FE_ + 4);
                jf[ridx][0] = j0.x; jf[ridx][1] = j0.y; jf[ridx][2] = j0.z; jf[ridx][3] = j0.w;
                jf[ridx][4] = j1.x; jf[ridx][5] = j1.y; jf[ridx][6] = j1.z; jf[ridx][7] = j1.w;
            }
            #pragma unroll
            for (int j = 0; j < 2; ++j) {
                const int colh = wv * 32 + j * 16 + lr;        // D-col = lane&15
                float gb[3], bh[3]; float4 w0[3], w1[3];
                #pragma unroll
                for (int g = 0; g < 3; ++g) {
                    const int idx = colh + (g << 7);
                    gb[g] = gi_base[b * G3_ + idx];
                    bh[g] = b_hh[idx];
                    w0[g] = *reinterpret_cast<const float4*>(W_ih + idx * 136 + 128);
                    w1[g] = *reinterpret_cast<const float4*>(W_ih + idx * 136 + 132);
                }
                #pragma unroll
                for (int ridx = 0; ridx < 4; ++ridx) {
                    float ig[3];
                    #pragma unroll
                    for (int g = 0; g < 3; ++g) {
                        ig[g] = gb[g]
                          + jf[ridx][0]*w0[g].x + jf[ridx][1]*w0[g].y
                          + jf[ridx][2]*w0[g].z + jf[ridx][3]*w0[g].w
                          + jf[ridx][4]*w1[g].x + jf[ridx][5]*w1[g].y
                          + jf[ridx][6]*w1[g].z + jf[ridx][7]*w1[g].w;
                    }
                    const float hr = acc[rt][j][0][ridx] + bh[0];
                    const float hz = acc[rt][j][1][ridx] + bh[1];
                    const float hn = acc[rt][j][2][ridx] + bh[2];
                    const float rr = 1.f / (1.f + __expf(-(ig[0] + hr)));
                    const float zz = 1.f / (1.f + __expf(-(ig[1] + hz)));
                    const float e2 = __expf(2.f * (ig[2] + rr * hn));
                    const float nn = 1.f - 2.f / (e2 + 1.f);   // tanh
                    const int rl = rp * 32 + rt * 16 + lq * 4 + ridx;
                    const float hv = Asf[(rl * H_ + colh) ^ ((rl & 7) << 2)];
                    out[(size_t)(row0 + rl) * H_ + colh] = (1.f - zz) * nn + zz * hv;
                }
            }
        }
    }
}

// ---------------------------------------------------------------------------
extern "C" void kernel_launch(void* const* d_in, const int* in_sizes, int n_in,
                              void* d_out, int out_size, void* d_ws, size_t ws_size,
                              hipStream_t stream) {
    const float* h    = (const float*)d_in[0];
    const float* jets = (const float*)d_in[1];
    // d_in[2] = mask: unused by the reference forward
    const float* Wm   = (const float*)d_in[3];
    const float* bm   = (const float*)d_in[4];
    const float* W_ih = (const float*)d_in[5];
    const float* W_hh = (const float*)d_in[6];
    const float* b_ih = (const float*)d_in[7];
    const float* b_hh = (const float*)d_in[8];
    float* out = (float*)d_out;

    // d_ws layout (rewritten every call; ~1.77 MB total):
    //   [0, 1.57MB)  gi_base  (B*3H f32)
    //   +1572864     Whi      (49152 u16, 16B-aligned)
    //   +1671168     Wlo      (49152 u16, 16B-aligned)
    float* gi_base      = (float*)d_ws;
    unsigned short* Whi = (unsigned short*)((char*)d_ws + 1572864);
    unsigned short* Wlo = (unsigned short*)((char*)d_ws + 1671168);

    k0_split<<<dim3(G3_ * H_ / 256), dim3(256), 0, stream>>>(W_hh, Whi, Wlo);
    k1_prep<<<dim3(B_), dim3(256), 0, stream>>>(h, Wm, bm, W_ih, b_ih, gi_base);
    k2_mfma<<<dim3(B_ * N_ / 64), dim3(256), 0, stream>>>(h, jets, Whi, Wlo,
                                                          b_hh, W_ih, gi_base, out);
}

// Round 8
// 263.707 us; speedup vs baseline: 1.3349x; 1.3349x over previous
//
#include <hip/hip_runtime.h>
#include <hip/hip_bf16.h>

#define B_   1024
#define N_   128
#define H_   128
#define FE_  8
#define G3_  384       // 3*H

typedef short s8v __attribute__((ext_vector_type(8)));   // 8 bf16 (4 VGPRs)
typedef float f4v __attribute__((ext_vector_type(4)));   // 4 fp32 accum

__device__ __forceinline__ unsigned short f2bf(float x) {  // RNE fp32->bf16
    unsigned int u = __float_as_uint(x);
    u += 0x7fffu + ((u >> 16) & 1u);
    return (unsigned short)(u >> 16);
}
__device__ __forceinline__ float bf2f(unsigned short s) {
    return __uint_as_float(((unsigned int)s) << 16);
}

// ---------------------------------------------------------------------------
// k1: per-jet precompute (fp32, audited) + folded weight-split preamble.
//   preamble: split W_hh (49152) and W_ih[:,128:136] (3072) into bf16 hi/lo.
//   hsum[b] = sum_n h[b,n,:]; message[b]=tanh(hsum.Wm^T + N*bm);
//   gi_base[b,g] = message[b].W_ih[g,0:128] + b_ih[g]
// ---------------------------------------------------------------------------
__global__ __launch_bounds__(256) void k1_prep(
    const float* __restrict__ h, const float* __restrict__ Wm,
    const float* __restrict__ bm, const float* __restrict__ W_ih,
    const float* __restrict__ W_hh, const float* __restrict__ b_ih,
    float* __restrict__ gi_base,
    unsigned short* __restrict__ Whi, unsigned short* __restrict__ Wlo,
    unsigned short* __restrict__ Wth, unsigned short* __restrict__ Wtl)
{
    const int b = blockIdx.x;
    const int t = threadIdx.x;

    // ---- folded weight split: 52224 elems over 1024 blocks x 51 ----
    if (t < 51) {
        const int i = b * 51 + t;                  // < 52224 always
        if (i < 49152) {
            const float x = W_hh[i];
            const unsigned short hb = f2bf(x);
            Whi[i] = hb;
            Wlo[i] = f2bf(x - bf2f(hb));
        } else {
            const int j = i - 49152;               // 0..3071
            const float x = W_ih[(j >> 3) * 136 + 128 + (j & 7)];
            const unsigned short hb = f2bf(x);
            Wth[j] = hb;
            Wtl[j] = f2bf(x - bf2f(hb));
        }
    }

    __shared__ __align__(16) float4 part[256];
    __shared__ __align__(16) float  hsum[H_];
    __shared__ __align__(16) float  msg[H_];

    const float4* h4 = reinterpret_cast<const float4*>(h + (size_t)b * (N_ * H_));
    const int kc = t & 31;
    const int ng = t >> 5;
    float4 s = make_float4(0.f, 0.f, 0.f, 0.f);
    #pragma unroll
    for (int i = 0; i < 16; ++i) {
        float4 v = h4[(ng * 16 + i) * 32 + kc];
        s.x += v.x; s.y += v.y; s.z += v.z; s.w += v.w;
    }
    part[t] = s;
    __syncthreads();
    if (t < 32) {
        float4 a = part[t];
        #pragma unroll
        for (int g = 1; g < 8; ++g) {
            float4 v = part[g * 32 + t];
            a.x += v.x; a.y += v.y; a.z += v.z; a.w += v.w;
        }
        reinterpret_cast<float4*>(hsum)[t] = a;
    }
    __syncthreads();

    if (t < H_) {
        const float4* wr  = reinterpret_cast<const float4*>(Wm + t * H_);
        const float4* hs4 = reinterpret_cast<const float4*>(hsum);
        float d = 0.f;
        #pragma unroll
        for (int j = 0; j < 32; ++j) {
            float4 w = wr[j]; float4 x = hs4[j];
            d += w.x * x.x + w.y * x.y + w.z * x.z + w.w * x.w;
        }
        d += (float)N_ * bm[t];
        msg[t] = tanhf(d);
    }
    __syncthreads();

    for (int g = t; g < G3_; g += 256) {
        const float4* wr = reinterpret_cast<const float4*>(W_ih + g * (H_ + FE_));
        const float4* m4 = reinterpret_cast<const float4*>(msg);
        float d = 0.f;
        #pragma unroll
        for (int j = 0; j < 32; ++j) {
            float4 w = wr[j]; float4 x = m4[j];
            d += w.x * x.x + w.y * x.y + w.z * x.z + w.w * x.w;
        }
        gi_base[b * G3_ + g] = d + b_ih[g];
    }
}

// ---------------------------------------------------------------------------
// k2: out = GRU(h, ...) with gh+jets-tail via split-bf16 MFMA (16x16x32).
// Block: 64 rows x 384 cols, 512 threads (8 waves). Wave wv owns the gate
// triple for cols wv*16..wv*16+15 (gate-rows col, col+128, col+256) so the
// GRU epilogue is wave-local. acc[rt][g] = gh_g + jets.Wt_g (r,z); the n-gate
// jets-tail goes to accT (i_n must stay separate from h_n for r*h_n).
// A (h) is cooperatively split hi/lo bf16 into LDS once per block; slots
// XOR-swizzled by (row&7) -> 2-way max on both ds_write and ds_read_b128.
// HW-verified MFMA layouts (round 7 passed): A lane=row(l&15),k=(l>>4)*8+e;
// B lane=col,k likewise; D col=l&15,row=(l>>4)*4+reg.
// ---------------------------------------------------------------------------
__global__ __launch_bounds__(512, 4) void k2_mfma(
    const float* __restrict__ h, const float* __restrict__ jets,
    const unsigned short* __restrict__ Whi, const unsigned short* __restrict__ Wlo,
    const unsigned short* __restrict__ Wth, const unsigned short* __restrict__ Wtl,
    const float* __restrict__ b_hh, const float* __restrict__ gi_base,
    float* __restrict__ out)
{
    __shared__ __align__(16) unsigned short Ah[64 * H_];   // 16 KB hi plane
    __shared__ __align__(16) unsigned short Al[64 * H_];   // 16 KB lo plane

    const int t    = threadIdx.x;
    const int row0 = blockIdx.x * 64;
    const int b    = row0 >> 7;
    const int wv   = t >> 6;             // wave 0..7 -> col slice
    const int l    = t & 63;
    const int lr   = l & 15;
    const int lq   = l >> 4;
    const int col  = wv * 16 + lr;       // output column (and D-col)

    // ---- stage A: fp32 h -> hi/lo bf16 planes, swizzled slots ----
    {
        const int r  = t >> 3;                  // 0..63
        const int kq = (t & 7) * 16;            // 0,16,...,112
        const float4* src = reinterpret_cast<const float4*>(
            h + (size_t)(row0 + r) * H_ + kq);
        float xs[16];
        #pragma unroll
        for (int i = 0; i < 4; ++i) {
            const float4 v = src[i];
            xs[i * 4 + 0] = v.x; xs[i * 4 + 1] = v.y;
            xs[i * 4 + 2] = v.z; xs[i * 4 + 3] = v.w;
        }
        #pragma unroll
        for (int c = 0; c < 2; ++c) {           // two 8-elem chunks
            s8v hv8, lv8;
            #pragma unroll
            for (int e = 0; e < 8; ++e) {
                const float x = xs[c * 8 + e];
                const unsigned short hb = f2bf(x);
                hv8[e] = (short)hb;
                lv8[e] = (short)f2bf(x - bf2f(hb));
            }
            const int s = ((kq >> 3) + c) ^ (r & 7);      // swizzled 16B slot
            *reinterpret_cast<s8v*>(&Ah[r * H_ + s * 8]) = hv8;
            *reinterpret_cast<s8v*>(&Al[r * H_ + s * 8]) = lv8;
        }
    }
    __syncthreads();

    // per-col constants for the epilogue (hoisted)
    float gb[3], bh3[3];
    #pragma unroll
    for (int g = 0; g < 3; ++g) {
        gb[g]  = gi_base[b * G3_ + (g << 7) + col];
        bh3[g] = b_hh[(g << 7) + col];
    }

    #pragma unroll
    for (int rp = 0; rp < 2; ++rp) {            // rows rp*32 .. rp*32+31
        f4v acc[2][3];                           // [rt][gate]
        f4v accT[2];                             // n-gate jets-tail
        #pragma unroll
        for (int rt = 0; rt < 2; ++rt) {
            #pragma unroll
            for (int g = 0; g < 3; ++g)
                #pragma unroll
                for (int e = 0; e < 4; ++e) acc[rt][g][e] = 0.f;
            #pragma unroll
            for (int e = 0; e < 4; ++e) accT[rt][e] = 0.f;
        }

        // ---- main K=128: 4 slices of 32 ----
        #pragma unroll
        for (int ks = 0; ks < 4; ++ks) {
            s8v aH[2], aL[2];
            #pragma unroll
            for (int rt = 0; rt < 2; ++rt) {
                const int r   = rp * 32 + rt * 16 + lr;
                const int idx = r * H_ + ((((ks << 2) + lq) ^ (r & 7)) << 3);
                aH[rt] = *reinterpret_cast<const s8v*>(&Ah[idx]);
                aL[rt] = *reinterpret_cast<const s8v*>(&Al[idx]);
            }
            #pragma unroll
            for (int g = 0; g < 3; ++g) {
                const int off = ((g << 7) + col) * H_ + ks * 32 + lq * 8;
                const s8v bH = *reinterpret_cast<const s8v*>(Whi + off);
                const s8v bL = *reinterpret_cast<const s8v*>(Wlo + off);
                #pragma unroll
                for (int rt = 0; rt < 2; ++rt) {
                    acc[rt][g] = __builtin_amdgcn_mfma_f32_16x16x32_bf16(
                        aH[rt], bH, acc[rt][g], 0, 0, 0);
                    acc[rt][g] = __builtin_amdgcn_mfma_f32_16x16x32_bf16(
                        aH[rt], bL, acc[rt][g], 0, 0, 0);
                    acc[rt][g] = __builtin_amdgcn_mfma_f32_16x16x32_bf16(
                        aL[rt], bH, acc[rt][g], 0, 0, 0);
                }
            }
        }

        // ---- jets tail (K 128..135): A nonzero only in lanes lq==0 ----
        s8v aTh[2], aTl[2];
        #pragma unroll
        for (int rt = 0; rt < 2; ++rt) {
            const int row = row0 + rp * 32 + rt * 16 + lr;
            const float4 j0 = *reinterpret_cast<const float4*>(jets + (size_t)row * FE_);
            const float4 j1 = *reinterpret_cast<const float4*>(jets + (size_t)row * FE_ + 4);
            const float jx[8] = {j0.x, j0.y, j0.z, j0.w, j1.x, j1.y, j1.z, j1.w};
            #pragma unroll
            for (int e = 0; e < 8; ++e) {
                const float x = (lq == 0) ? jx[e] : 0.f;
                const unsigned short hb = f2bf(x);
                aTh[rt][e] = (short)hb;
                aTl[rt][e] = (short)f2bf(x - bf2f(hb));
            }
        }
        #pragma unroll
        for (int g = 0; g < 3; ++g) {
            // all lq lanes read the same 16B (k>=8 contributions are 0 via A)
            const int gi = (g << 7) + col;
            const s8v bTh = *reinterpret_cast<const s8v*>(Wth + gi * 8);
            const s8v bTl = *reinterpret_cast<const s8v*>(Wtl + gi * 8);
            #pragma unroll
            for (int rt = 0; rt < 2; ++rt) {
                if (g < 2) {
                    acc[rt][g] = __builtin_amdgcn_mfma_f32_16x16x32_bf16(
                        aTh[rt], bTh, acc[rt][g], 0, 0, 0);
                    acc[rt][g] = __builtin_amdgcn_mfma_f32_16x16x32_bf16(
                        aTh[rt], bTl, acc[rt][g], 0, 0, 0);
                    acc[rt][g] = __builtin_amdgcn_mfma_f32_16x16x32_bf16(
                        aTl[rt], bTh, acc[rt][g], 0, 0, 0);
                } else {
                    accT[rt] = __builtin_amdgcn_mfma_f32_16x16x32_bf16(
                        aTh[rt], bTh, accT[rt], 0, 0, 0);
                    accT[rt] = __builtin_amdgcn_mfma_f32_16x16x32_bf16(
                        aTh[rt], bTl, accT[rt], 0, 0, 0);
                    accT[rt] = __builtin_amdgcn_mfma_f32_16x16x32_bf16(
                        aTl[rt], bTh, accT[rt], 0, 0, 0);
                }
            }
        }

        // ---- GRU epilogue ----
        #pragma unroll
        for (int rt = 0; rt < 2; ++rt) {
            #pragma unroll
            for (int ridx = 0; ridx < 4; ++ridx) {
                const int rl  = rp * 32 + rt * 16 + lq * 4 + ridx;  // D-row
                const size_t row = (size_t)(row0 + rl);
                const float rr = 1.f / (1.f + __expf(-(gb[0] + bh3[0] + acc[rt][0][ridx])));
                const float zz = 1.f / (1.f + __expf(-(gb[1] + bh3[1] + acc[rt][1][ridx])));
                const float i_n = gb[2] + accT[rt][ridx];
                const float h_n = acc[rt][2][ridx] + bh3[2];
                const float e2  = __expf(2.f * (i_n + rr * h_n));
                const float nn  = 1.f - 2.f / (e2 + 1.f);            // tanh
                const float hv  = h[row * H_ + col];                 // exact h
                out[row * H_ + col] = (1.f - zz) * nn + zz * hv;
            }
        }
    }
}

// ---------------------------------------------------------------------------
extern "C" void kernel_launch(void* const* d_in, const int* in_sizes, int n_in,
                              void* d_out, int out_size, void* d_ws, size_t ws_size,
                              hipStream_t stream) {
    const float* h    = (const float*)d_in[0];
    const float* jets = (const float*)d_in[1];
    // d_in[2] = mask: unused by the reference forward
    const float* Wm   = (const float*)d_in[3];
    const float* bm   = (const float*)d_in[4];
    const float* W_ih = (const float*)d_in[5];
    const float* W_hh = (const float*)d_in[6];
    const float* b_ih = (const float*)d_in[7];
    const float* b_hh = (const float*)d_in[8];
    float* out = (float*)d_out;

    // d_ws layout (~1.79 MB, rewritten every call; all 16B-aligned):
    float* gi_base      = (float*)d_ws;                               // 1572864 B
    unsigned short* Whi = (unsigned short*)((char*)d_ws + 1572864);   //   98304 B
    unsigned short* Wlo = (unsigned short*)((char*)d_ws + 1671168);   //   98304 B
    unsigned short* Wth = (unsigned short*)((char*)d_ws + 1769472);   //    6144 B
    unsigned short* Wtl = (unsigned short*)((char*)d_ws + 1775616);   //    6144 B

    k1_prep<<<dim3(B_), dim3(256), 0, stream>>>(h, Wm, bm, W_ih, W_hh, b_ih,
                                                gi_base, Whi, Wlo, Wth, Wtl);
    k2_mfma<<<dim3(B_ * N_ / 64), dim3(512), 0, stream>>>(h, jets, Whi, Wlo,
                                                          Wth, Wtl, b_hh,
                                                          gi_base, out);
}